// Round 19
// baseline (317.977 us; speedup 1.0000x reference)
//
#include <hip/hip_runtime.h>

typedef unsigned short u16;
typedef unsigned int u32;
typedef u16 u16x8 __attribute__((ext_vector_type(8)));
typedef u16 u16x4 __attribute__((ext_vector_type(4)));
typedef float f32x4 __attribute__((ext_vector_type(4)));
typedef __bf16 bf16x8 __attribute__((ext_vector_type(8)));

#define NHEAD 12
#define NT 261
#define NGL 197
#define CDIM 768
#define KT 14
#define PS_STRIDE 232
#define VT_STRIDE 232

__device__ __forceinline__ float bf2f(u16 u) {
    u32 x = ((u32)u) << 16;
    float f;
    __builtin_memcpy(&f, &x, 4);
    return f;
}
__device__ __forceinline__ u16 f2bf(float f) {
    u32 x;
    __builtin_memcpy(&x, &f, 4);
    x = (x + 0x7fffu + ((x >> 16) & 1u)) >> 16;
    return (u16)x;
}

#define GLD_LDS16(g, l) \
    __builtin_amdgcn_global_load_lds((const __attribute__((address_space(1))) void*)(g), \
                                     (__attribute__((address_space(3))) void*)(l), 16, 0, 0)
#define WAITV(n) asm volatile("s_waitcnt vmcnt(" #n ")" ::: "memory")
#define BARM() asm volatile("s_barrier" ::: "memory")

struct CvArgs {
    const float* in[4];
    u16* out[4];
    int n4[4];
};

// ---------------- wave-per-row LayerNorm, fp32 input ----------------
__device__ __forceinline__ void ln_row(const float* __restrict__ in, const float* __restrict__ w,
                                       const float* __restrict__ bia, u16* __restrict__ out,
                                       int row, int lane) {
    const float4* r = (const float4*)(in + (size_t)row * CDIM);
    float4 a = r[lane], b4 = r[lane + 64], c4 = r[lane + 128];
    float s  = a.x + a.y + a.z + a.w + b4.x + b4.y + b4.z + b4.w + c4.x + c4.y + c4.z + c4.w;
    float ss = a.x*a.x + a.y*a.y + a.z*a.z + a.w*a.w
             + b4.x*b4.x + b4.y*b4.y + b4.z*b4.z + b4.w*b4.w
             + c4.x*c4.x + c4.y*c4.y + c4.z*c4.z + c4.w*c4.w;
#pragma unroll
    for (int off = 32; off; off >>= 1) {
        s  += __shfl_xor(s, off);
        ss += __shfl_xor(ss, off);
    }
    float mu = s * (1.f / 768.f);
    float var = ss * (1.f / 768.f) - mu * mu;
    float inv = rsqrtf(var + 1e-5f);
    const float4* wp = (const float4*)w;
    const float4* bp = (const float4*)bia;
    u16* o = out + (size_t)row * CDIM;
#pragma unroll
    for (int t = 0; t < 3; ++t) {
        float4 v = (t == 0) ? a : (t == 1) ? b4 : c4;
        float4 ww = wp[lane + t * 64], bb = bp[lane + t * 64];
        u16x4 ov;
        ov[0] = f2bf((v.x - mu) * inv * ww.x + bb.x);
        ov[1] = f2bf((v.y - mu) * inv * ww.y + bb.y);
        ov[2] = f2bf((v.z - mu) * inv * ww.z + bb.z);
        ov[3] = f2bf((v.w - mu) * inv * ww.w + bb.w);
        *(u16x4*)(o + t * 256 + lane * 4) = ov;
    }
}

// ---------------- wave-per-row LayerNorm, bf16 input (x1) ----------------
__device__ __forceinline__ void ln_row_bf(const u16* __restrict__ in, const float* __restrict__ w,
                                          const float* __restrict__ bia, u16* __restrict__ out,
                                          int row, int lane) {
    const u16* r = in + (size_t)row * CDIM;
    float v[12];
#pragma unroll
    for (int t = 0; t < 3; ++t) {
        u16x4 u = *(const u16x4*)(r + t * 256 + lane * 4);
#pragma unroll
        for (int j = 0; j < 4; ++j) v[t * 4 + j] = bf2f(u[j]);
    }
    float s = 0.f, ss = 0.f;
#pragma unroll
    for (int j = 0; j < 12; ++j) { s += v[j]; ss += v[j] * v[j]; }
#pragma unroll
    for (int off = 32; off; off >>= 1) {
        s  += __shfl_xor(s, off);
        ss += __shfl_xor(ss, off);
    }
    float mu = s * (1.f / 768.f);
    float var = ss * (1.f / 768.f) - mu * mu;
    float inv = rsqrtf(var + 1e-5f);
    const float4* wp = (const float4*)w;
    const float4* bp = (const float4*)bia;
    u16* o = out + (size_t)row * CDIM;
#pragma unroll
    for (int t = 0; t < 3; ++t) {
        float4 ww = wp[lane + t * 64], bb = bp[lane + t * 64];
        u16x4 ov;
        ov[0] = f2bf((v[t * 4 + 0] - mu) * inv * ww.x + bb.x);
        ov[1] = f2bf((v[t * 4 + 1] - mu) * inv * ww.y + bb.y);
        ov[2] = f2bf((v[t * 4 + 2] - mu) * inv * ww.z + bb.z);
        ov[3] = f2bf((v[t * 4 + 3] - mu) * inv * ww.w + bb.w);
        *(u16x4*)(o + t * 256 + lane * 4) = ov;
    }
}

// y=0: weight fp32->bf16 conversion; y=1: LN1 (4 rows/block)
__global__ __launch_bounds__(256) void pre_k(const float* __restrict__ x, const float* __restrict__ w,
                                             const float* __restrict__ bia, u16* __restrict__ out,
                                             int nrows, CvArgs cv) {
    if (blockIdx.y == 0) {
        int i = blockIdx.x * 256 + threadIdx.x;
        int s0 = cv.n4[0], s1 = s0 + cv.n4[1], s2 = s1 + cv.n4[2], s3 = s2 + cv.n4[3];
        const float* in;
        u16* o;
        int base;
        if (i < s0)      { in = cv.in[0]; o = cv.out[0]; base = 0; }
        else if (i < s1) { in = cv.in[1]; o = cv.out[1]; base = s0; }
        else if (i < s2) { in = cv.in[2]; o = cv.out[2]; base = s1; }
        else if (i < s3) { in = cv.in[3]; o = cv.out[3]; base = s2; }
        else return;
        int j = i - base;
        float4 v = ((const float4*)in)[j];
        u16x4 ov;
        ov[0] = f2bf(v.x); ov[1] = f2bf(v.y); ov[2] = f2bf(v.z); ov[3] = f2bf(v.w);
        ((u16x4*)o)[j] = ov;
    } else {
        int lane = threadIdx.x & 63, wv = threadIdx.x >> 6;
        int row = blockIdx.x * 4 + wv;
        if (row < nrows) ln_row(x, w, bia, out, row, lane);
    }
}

__global__ __launch_bounds__(256) void ln_wbf(const u16* __restrict__ in, const float* __restrict__ w,
                                              const float* __restrict__ bia, u16* __restrict__ out, int nrows) {
    int lane = threadIdx.x & 63, wv = threadIdx.x >> 6;
    int row = blockIdx.x * 4 + wv;
    if (row < nrows) ln_row_bf(in, w, bia, out, row, lane);
}

// ---------------- 1-wave barrier-free GEMM: 64x64 tile, BK=32, 16 KB LDS ----------------
// 64 threads = 1 wave; no s_barrier at all (single-wave LDS pipeline: compiler's lgkmcnt
// before step-t MFMAs drains ds_reads before stage(t+1) issues -> 2-slot WAR safe).
// Counted ledger: 8 gld_lds/stage; WAITV(8) at step top = stage(t) landed, t+1 in flight.
// Same involution swizzle as gemm11 (valid: (base+l15)>>1 &3 == (l15>>1)&3 for base%16==0).
// Grid 131 x (N/64) -> 1572 blocks for N=768: ~6 evenly-spread waves/CU on proj/fc2.
// EPI: 1 = +bias +resid(fp32) -> bf16; 3 = +bias +resid(bf16) -> fp32
template <int EPI>
__global__ __launch_bounds__(64, 4) void gemm15(const u16* __restrict__ A, const u16* __restrict__ Bw,
                                                int M, int N, int K, int nbn,
                                                const float* __restrict__ bias,
                                                const void* __restrict__ resid, void* __restrict__ outp) {
    __shared__ __align__(16) u16 sm[2][4096];   // [slot][A 2048 | B 2048] u16 = 16 KiB
    const int lane = threadIdx.x;
    const int nwg = gridDim.x;
    const int q = nwg >> 3, r = nwg & 7;
    const int xcd = blockIdx.x & 7, within = blockIdx.x >> 3;
    const int id2 = (xcd < r ? xcd * (q + 1) : r * (q + 1) + (xcd - r) * q) + within;
    const int bm = id2 / nbn, bn = id2 % nbn;
    const int l15 = lane & 15, lg = lane >> 4;
    const int arow0 = bm * 64, brow0 = bn * 64;
    const int nt = K >> 5;

    const int srow = lane >> 2;                 // 0..15
    const int sslot = lane & 3;
    const int sk = (sslot ^ ((srow >> 1) & 3)) * 8;
    const u16* gA[4];
    const u16* gB[4];
#pragma unroll
    for (int i = 0; i < 4; ++i) {
        int ar = arow0 + i * 16 + srow;
        if (ar >= M) ar = M - 1;
        gA[i] = A + (size_t)ar * K + sk;
        gB[i] = Bw + (size_t)(brow0 + i * 16 + srow) * K + sk;
    }

    auto STAGE = [&](int tt) {
        u16* sb = sm[tt & 1];
        const size_t ko = (size_t)tt * 32;
#pragma unroll
        for (int i = 0; i < 4; ++i) GLD_LDS16(gA[i] + ko, sb + i * 512 + lane * 8);
#pragma unroll
        for (int i = 0; i < 4; ++i) GLD_LDS16(gB[i] + ko, sb + 2048 + i * 512 + lane * 8);
    };

    f32x4 acc[4][4] = {};
    const int xb = (l15 >> 1) & 3;

    STAGE(0);
    for (int t = 0; t < nt; ++t) {
        if (t + 1 < nt) {
            STAGE(t + 1);
            WAITV(8);                           // stage(t) landed; stage(t+1)'s 8 in flight
        } else {
            WAITV(0);
        }
        const u16* sb = sm[t & 1];
        bf16x8 af[4], bq[4];
#pragma unroll
        for (int mi = 0; mi < 4; ++mi)
            af[mi] = *(const bf16x8*)(sb + (mi * 16 + l15) * 32 + ((lg ^ xb) * 8));
#pragma unroll
        for (int ni = 0; ni < 4; ++ni)
            bq[ni] = *(const bf16x8*)(sb + 2048 + (ni * 16 + l15) * 32 + ((lg ^ xb) * 8));
#pragma unroll
        for (int mi = 0; mi < 4; ++mi)
#pragma unroll
            for (int ni = 0; ni < 4; ++ni)
                acc[mi][ni] = __builtin_amdgcn_mfma_f32_16x16x32_bf16(af[mi], bq[ni], acc[mi][ni], 0, 0, 0);
    }

#pragma unroll
    for (int mi = 0; mi < 4; ++mi) {
        int row0 = arow0 + mi * 16 + lg * 4;
#pragma unroll
        for (int ni = 0; ni < 4; ++ni) {
            int col = brow0 + ni * 16 + l15;
            float bb = bias[col];
#pragma unroll
            for (int rr = 0; rr < 4; ++rr) {
                int row = row0 + rr;
                if (row < M) {
                    float v = acc[mi][ni][rr] + bb;
                    if (EPI == 1) {
                        v += ((const float*)resid)[(size_t)row * N + col];
                        ((u16*)outp)[(size_t)row * N + col] = f2bf(v);
                    } else {
                        v += bf2f(((const u16*)resid)[(size_t)row * N + col]);
                        ((float*)outp)[(size_t)row * N + col] = v;
                    }
                }
            }
        }
    }
}

// ---------------- fc1 GEMM (r18-proven): 128x256 block, 8 waves, BK=32, 48 KB LDS ------------
__global__ __launch_bounds__(512, 3) void gemm14(const u16* __restrict__ A, const u16* __restrict__ Bw,
                                                 int M, int N, int K, int nbn,
                                                 const float* __restrict__ bias, void* __restrict__ outp) {
    __shared__ __align__(16) u16 sm[2][12288];
    const int tid = threadIdx.x;
    const int nwg = gridDim.x;
    const int q = nwg >> 3, r = nwg & 7;
    const int xcd = blockIdx.x & 7, within = blockIdx.x >> 3;
    const int id2 = (xcd < r ? xcd * (q + 1) : r * (q + 1) + (xcd - r) * q) + within;
    const int bm = id2 / nbn, bn = id2 % nbn;
    const int lane = tid & 63, wv = tid >> 6;
    const int wr = wv >> 2, wc = wv & 3;
    const int l15 = lane & 15, lg = lane >> 4;
    const int arow0 = bm * 128, brow0 = bn * 256;
    const int nt = K >> 5;

    const int srow = tid >> 2;
    const int sslot = tid & 3;
    const int sk = (sslot ^ ((srow >> 1) & 3)) * 8;
    int ar0 = arow0 + srow; if (ar0 >= M) ar0 = M - 1;
    const u16* gA0 = A + (size_t)ar0 * K + sk;
    const u16* gB[2];
#pragma unroll
    for (int i = 0; i < 2; ++i)
        gB[i] = Bw + (size_t)(brow0 + i * 128 + srow) * K + sk;

    auto STAGE = [&](int tt) {
        u16* sb = sm[tt & 1];
        const size_t ko = (size_t)tt * 32;
        GLD_LDS16(gA0 + ko, sb + tid * 8);
#pragma unroll
        for (int i = 0; i < 2; ++i)
            GLD_LDS16(gB[i] + ko, sb + 4096 + i * 4096 + tid * 8);
    };

    f32x4 acc[4][4] = {};
    const int xb = (l15 >> 1) & 3;

    STAGE(0);
    for (int t = 0; t < nt; ++t) {
        if (t + 1 < nt) {
            STAGE(t + 1);
            WAITV(3);
        } else {
            WAITV(0);
        }
        BARM();
        const u16* sb = sm[t & 1];
        bf16x8 af[4], bq[4];
#pragma unroll
        for (int mi = 0; mi < 4; ++mi)
            af[mi] = *(const bf16x8*)(sb + (wr * 64 + mi * 16 + l15) * 32 + ((lg ^ xb) * 8));
#pragma unroll
        for (int ni = 0; ni < 4; ++ni)
            bq[ni] = *(const bf16x8*)(sb + 4096 + (wc * 64 + ni * 16 + l15) * 32 + ((lg ^ xb) * 8));
#pragma unroll
        for (int mi = 0; mi < 4; ++mi)
#pragma unroll
            for (int ni = 0; ni < 4; ++ni)
                acc[mi][ni] = __builtin_amdgcn_mfma_f32_16x16x32_bf16(af[mi], bq[ni], acc[mi][ni], 0, 0, 0);
        if (t + 2 < nt) BARM();
    }

#pragma unroll
    for (int mi = 0; mi < 4; ++mi) {
        int row0 = arow0 + wr * 64 + mi * 16 + lg * 4;
#pragma unroll
        for (int ni = 0; ni < 4; ++ni) {
            int col = brow0 + wc * 64 + ni * 16 + l15;
            float bb = bias[col];
#pragma unroll
            for (int rr = 0; rr < 4; ++rr) {
                int row = row0 + rr;
                if (row < M) {
                    float v = acc[mi][ni][rr] + bb;
                    float z = v + 0.044715f * v * v * v;
                    v = v / (1.f + __expf(-1.5957691216f * z));
                    ((u16*)outp)[(size_t)row * N + col] = f2bf(v);
                }
            }
        }
    }
}

// ---------------- qkv GEMM, two zones (r17-proven) ----------------
__global__ __launch_bounds__(256, 4) void gemm_qkv(const u16* __restrict__ A, const u16* __restrict__ Bw,
                                                   u16* __restrict__ outp) {
    __shared__ __align__(16) u16 sm[2][8192];
    const int tid = threadIdx.x;
    const int nwg = gridDim.x;                  // 996
    const int q = nwg >> 3, r = nwg & 7;
    const int xcd = blockIdx.x & 7, within = blockIdx.x >> 3;
    const int id2 = (xcd < r ? xcd * (q + 1) : r * (q + 1) + (xcd - r) * q) + within;
    const bool kvz = (id2 >= 396);
    const int idz = kvz ? id2 - 396 : id2;
    const int bm = kvz ? idz / 12 : idz / 6;
    const int bn = kvz ? idz % 12 : idz % 6;
    const int Mz = kvz ? 6304 : 8352;
    const int colbase = kvz ? 768 + bn * 128 : bn * 128;
    const int lane = tid & 63, wv = tid >> 6;
    const int wr = wv >> 1, wc = wv & 1;
    const int l15 = lane & 15, lg = lane >> 4;
    const int arow0 = bm * 128;
    const int K = 768;
    const int nt = 24;

    const int srow = tid >> 2;
    const int sslot = tid & 3;
    const int sk = (sslot ^ ((srow >> 1) & 3)) * 8;
    const u16* gA[2];
    const u16* gB[2];
#pragma unroll
    for (int i = 0; i < 2; ++i) {
        int ar = arow0 + i * 64 + srow;
        if (ar >= Mz) ar = Mz - 1;
        int real = kvz ? (ar / 197) * 261 + (ar % 197) : ar;
        gA[i] = A + (size_t)real * K + sk;
        gB[i] = Bw + (size_t)(colbase + i * 64 + srow) * K + sk;
    }

    auto STAGE = [&](int tt) {
        u16* sb = sm[tt & 1];
        const size_t ko = (size_t)tt * 32;
#pragma unroll
        for (int i = 0; i < 2; ++i) GLD_LDS16(gA[i] + ko, sb + i * 2048 + tid * 8);
#pragma unroll
        for (int i = 0; i < 2; ++i) GLD_LDS16(gB[i] + ko, sb + 4096 + i * 2048 + tid * 8);
    };

    f32x4 acc[4][4] = {};
    const int xb = (l15 >> 1) & 3;

    STAGE(0);
    for (int t = 0; t < nt; ++t) {
        if (t + 1 < nt) {
            STAGE(t + 1);
            WAITV(4);
        } else {
            WAITV(0);
        }
        BARM();
        const u16* sb = sm[t & 1];
        bf16x8 af[4], bq[4];
#pragma unroll
        for (int mi = 0; mi < 4; ++mi)
            af[mi] = *(const bf16x8*)(sb + (wr * 64 + mi * 16 + l15) * 32 + ((lg ^ xb) * 8));
#pragma unroll
        for (int ni = 0; ni < 4; ++ni)
            bq[ni] = *(const bf16x8*)(sb + 4096 + (wc * 64 + ni * 16 + l15) * 32 + ((lg ^ xb) * 8));
#pragma unroll
        for (int mi = 0; mi < 4; ++mi)
#pragma unroll
            for (int ni = 0; ni < 4; ++ni)
                acc[mi][ni] = __builtin_amdgcn_mfma_f32_16x16x32_bf16(af[mi], bq[ni], acc[mi][ni], 0, 0, 0);
        if (t + 2 < nt) BARM();
    }

#pragma unroll
    for (int mi = 0; mi < 4; ++mi) {
        int row0 = arow0 + wr * 64 + mi * 16 + lg * 4;
#pragma unroll
        for (int ni = 0; ni < 4; ++ni) {
            int col = colbase + wc * 64 + ni * 16 + l15;
#pragma unroll
            for (int rr = 0; rr < 4; ++rr) {
                int row = row0 + rr;
                if (row < Mz) {
                    int real = kvz ? (row / 197) * 261 + (row % 197) : row;
                    outp[(size_t)real * 2304 + col] = f2bf(acc[mi][ni][rr]);
                }
            }
        }
    }
}

// ---------------- Fused attention (r8-proven): [0,1536) global MFMA, [1536,2048) neighborhood --
__global__ __launch_bounds__(256) void attn_fused(const u16* __restrict__ qkv, const float* __restrict__ ps,
                                                  u16* __restrict__ Z) {
    __shared__ __align__(16) u16 lds0[4 * 16 * PS_STRIDE];
    __shared__ __align__(16) u16 Vt[64 * VT_STRIDE];
    const int tid = threadIdx.x;
    const int lane = tid & 63, wv = tid >> 6;

    if (blockIdx.x >= 1536) {
        int idx = blockIdx.x - 1536;
        int b = idx >> 4;
        int m = (idx & 15) * 4 + wv;
        float px = ps[((size_t)b * 64 + m) * 2 + 0] * (1.f / 16.f);
        float py = ps[((size_t)b * 64 + m) * 2 + 1] * (1.f / 16.f);
        int c0 = min(max((int)floorf(px), 0), 13);
        int c1 = min(max((int)ceilf(px), 0), 13);
        int r0 = min(max((int)floorf(py), 0), 13);
        int r1 = min(max((int)ceilf(py), 0), 13);
        int tok[4];
        tok[0] = 1 + r0 * 14 + c0;
        tok[1] = 1 + r1 * 14 + c0;
        tok[2] = 1 + r0 * 14 + c1;
        tok[3] = 1 + r1 * 14 + c1;
        const size_t rowq = ((size_t)b * NT + NGL + m) * 2304;
#pragma unroll 1
        for (int h = 0; h < NHEAD; ++h) {
            float qv = bf2f(qkv[rowq + h * 64 + lane]);
            float a[4];
#pragma unroll
            for (int j = 0; j < 4; ++j) {
                float p = qv * bf2f(qkv[((size_t)b * NT + tok[j]) * 2304 + 768 + h * 64 + lane]);
#pragma unroll
                for (int off = 32; off; off >>= 1) p += __shfl_xor(p, off);
                a[j] = p;
            }
            float mx = fmaxf(fmaxf(a[0], a[1]), fmaxf(a[2], a[3]));
            float e0 = expf(a[0] - mx), e1 = expf(a[1] - mx), e2 = expf(a[2] - mx), e3 = expf(a[3] - mx);
            float inv = 1.f / (e0 + e1 + e2 + e3);
            float v0 = bf2f(qkv[((size_t)b * NT + tok[0]) * 2304 + 1536 + h * 64 + lane]);
            float v1 = bf2f(qkv[((size_t)b * NT + tok[1]) * 2304 + 1536 + h * 64 + lane]);
            float v2 = bf2f(qkv[((size_t)b * NT + tok[2]) * 2304 + 1536 + h * 64 + lane]);
            float v3 = bf2f(qkv[((size_t)b * NT + tok[3]) * 2304 + 1536 + h * 64 + lane]);
            float o = (e0 * v0 + e1 * v1 + e2 * v2 + e3 * v3) * inv;
            Z[((size_t)b * NT + NGL + m) * CDIM + h * 64 + lane] = f2bf(o);
        }
        return;
    }

    const int blk = blockIdx.x;
    const int qt = blk & 3;
    const int bh = blk >> 2;
    const int h = bh % NHEAD, b = bh / NHEAD;
    const int l15 = lane & 15, lg = lane >> 4;
    const u16* base = qkv + (size_t)b * NT * 2304;

    for (int c = tid; c < 224 * 8; c += 256) {
        int row = c >> 3, ch = c & 7;
        u16x8 v = {};
        if (row < NGL) v = *(const u16x8*)(base + (size_t)row * 2304 + 768 + h * 64 + ch * 8);
        int byte = row * 128 + ((ch * 16) ^ ((row & 7) << 4));
        *(u16x8*)((char*)lds0 + byte) = v;
    }
    for (int c = tid; c < 112 * 8; c += 256) {
        int mp = c >> 3, dch = c & 7;
        int m0 = mp * 2;
        u16x8 a0 = {}, a1 = {};
        if (m0 < NGL)     a0 = *(const u16x8*)(base + (size_t)m0 * 2304 + 1536 + h * 64 + dch * 8);
        if (m0 + 1 < NGL) a1 = *(const u16x8*)(base + (size_t)(m0 + 1) * 2304 + 1536 + h * 64 + dch * 8);
#pragma unroll
        for (int j = 0; j < 8; ++j) {
            u32 pk = (u32)a0[j] | ((u32)a1[j] << 16);
            *(u32*)((char*)Vt + (size_t)(dch * 8 + j) * (VT_STRIDE * 2) + m0 * 2) = pk;
        }
    }
    const int q0 = qt * 64 + wv * 16;
    int qrow = q0 + l15; if (qrow > NGL - 1) qrow = NGL - 1;
    bf16x8 aq0 = *(const bf16x8*)(base + (size_t)qrow * 2304 + h * 64 + lg * 8);
    bf16x8 aq1 = *(const bf16x8*)(base + (size_t)qrow * 2304 + h * 64 + 32 + lg * 8);
    __syncthreads();

    f32x4 s[KT];
    const int sw = (l15 & 7) << 4;
#pragma unroll
    for (int t = 0; t < KT; ++t) {
        const char* krow = (const char*)lds0 + (t * 16 + l15) * 128;
        bf16x8 bk0 = *(const bf16x8*)(krow + ((lg * 16) ^ sw));
        bf16x8 bk1 = *(const bf16x8*)(krow + ((64 + lg * 16) ^ sw));
        f32x4 acc = {};
        acc = __builtin_amdgcn_mfma_f32_16x16x32_bf16(aq0, bk0, acc, 0, 0, 0);
        acc = __builtin_amdgcn_mfma_f32_16x16x32_bf16(aq1, bk1, acc, 0, 0, 0);
        s[t] = acc * 0.125f;
    }
    float mx[4] = {-1e30f, -1e30f, -1e30f, -1e30f};
#pragma unroll
    for (int t = 0; t < KT; ++t)
#pragma unroll
        for (int r = 0; r < 4; ++r) mx[r] = fmaxf(mx[r], s[t][r]);
#pragma unroll
    for (int off = 1; off < 16; off <<= 1)
#pragma unroll
        for (int r = 0; r < 4; ++r) mx[r] = fmaxf(mx[r], __shfl_xor(mx[r], off));
    float sum[4] = {};
#pragma unroll
    for (int t = 0; t < KT; ++t) {
        bool valid = (t * 16 + l15) < NGL;
#pragma unroll
        for (int r = 0; r < 4; ++r) {
            float e = valid ? __expf(s[t][r] - mx[r]) : 0.f;
            s[t][r] = e;
            sum[r] += e;
        }
    }
#pragma unroll
    for (int off = 1; off < 16; off <<= 1)
#pragma unroll
        for (int r = 0; r < 4; ++r) sum[r] += __shfl_xor(sum[r], off);
    float inv[4];
#pragma unroll
    for (int r = 0; r < 4; ++r) inv[r] = 1.f / sum[r];

    __syncthreads();
    u16* Pw = lds0 + wv * 16 * PS_STRIDE;
#pragma unroll
    for (int t = 0; t < KT; ++t)
#pragma unroll
        for (int r = 0; r < 4; ++r)
            Pw[(4 * lg + r) * PS_STRIDE + t * 16 + l15] = f2bf(s[t][r] * inv[r]);

    f32x4 o[4] = {};
#pragma unroll
    for (int ks = 0; ks < 7; ++ks) {
        bf16x8 pa = *(const bf16x8*)(Pw + l15 * PS_STRIDE + ks * 32 + lg * 8);
#pragma unroll
        for (int dt = 0; dt < 4; ++dt) {
            bf16x8 bv = *(const bf16x8*)((const char*)Vt + (size_t)(dt * 16 + l15) * (VT_STRIDE * 2) + ks * 64 + lg * 16);
            o[dt] = __builtin_amdgcn_mfma_f32_16x16x32_bf16(pa, bv, o[dt], 0, 0, 0);
        }
    }
#pragma unroll
    for (int dt = 0; dt < 4; ++dt)
#pragma unroll
        for (int r = 0; r < 4; ++r) {
            int q = q0 + 4 * lg + r;
            if (q < NGL) Z[((size_t)b * NT + q) * CDIM + h * 64 + dt * 16 + l15] = f2bf(o[dt][r]);
        }
}

extern "C" void kernel_launch(void* const* d_in, const int* in_sizes, int n_in,
                              void* d_out, int out_size, void* d_ws, size_t ws_size,
                              hipStream_t stream) {
    const float* x      = (const float*)d_in[0];
    const float* ps     = (const float*)d_in[1];
    const float* n1w    = (const float*)d_in[3];
    const float* n1b    = (const float*)d_in[4];
    const float* qkv_w  = (const float*)d_in[5];
    const float* proj_w = (const float*)d_in[6];
    const float* proj_b = (const float*)d_in[7];
    const float* n2w    = (const float*)d_in[8];
    const float* n2b    = (const float*)d_in[9];
    const float* fc1_w  = (const float*)d_in[10];
    const float* fc1_b  = (const float*)d_in[11];
    const float* fc2_w  = (const float*)d_in[12];
    const float* fc2_b  = (const float*)d_in[13];

    char* ws = (char*)d_ws;
    const int M = 32 * NT;  // 8352
    u16* hbuf  = (u16*)ws;                               // 12,828,672 B
    u16* qkvb  = (u16*)(ws + 12828672);                  // 38,486,016 B
    u16* Zb    = (u16*)(ws + 12828672 + 38486016);       // 12,828,672 B
    u16* Gb    = (u16*)(ws + 12828672);                  // 51,314,688 B (aliases qkv+Z, both dead)
    u16* x1    = (u16*)(ws + 64143360);                  // bf16, 12,828,672 B
    u16* wq    = (u16*)(ws + 89800704);
    u16* wp    = wq + 2304 * 768;
    u16* w1    = wp + 768 * 768;
    u16* w2    = w1 + 3072 * 768;

    CvArgs cv;
    cv.in[0] = qkv_w;  cv.out[0] = wq; cv.n4[0] = 2304 * 768 / 4;
    cv.in[1] = proj_w; cv.out[1] = wp; cv.n4[1] = 768 * 768 / 4;
    cv.in[2] = fc1_w;  cv.out[2] = w1; cv.n4[2] = 3072 * 768 / 4;
    cv.in[3] = fc2_w;  cv.out[3] = w2; cv.n4[3] = 768 * 3072 / 4;

    pre_k<<<dim3(6912, 2), 256, 0, stream>>>(x, n1w, n1b, hbuf, M, cv);
    gemm_qkv<<<996, 256, 0, stream>>>(hbuf, wq, qkvb);
    attn_fused<<<2048, 256, 0, stream>>>(qkvb, ps, Zb);
    gemm15<1><<<131 * 12, 64, 0, stream>>>(Zb, wp, M, 768, 768, 12, proj_b, x, x1);
    ln_wbf<<<2088, 256, 0, stream>>>(x1, n2w, n2b, hbuf, M);
    gemm14<<<66 * 12, 512, 0, stream>>>(hbuf, w1, M, 3072, 768, 12, fc1_b, Gb);
    gemm15<3><<<131 * 12, 64, 0, stream>>>(Gb, w2, M, 768, 3072, 12, fc2_b, x1, (float*)d_out);
}

// Round 20
// 267.370 us; speedup vs baseline: 1.1893x; 1.1893x over previous
//
#include <hip/hip_runtime.h>

typedef unsigned short u16;
typedef unsigned int u32;
typedef u16 u16x8 __attribute__((ext_vector_type(8)));
typedef u16 u16x4 __attribute__((ext_vector_type(4)));
typedef float f32x4 __attribute__((ext_vector_type(4)));
typedef __bf16 bf16x8 __attribute__((ext_vector_type(8)));

#define NHEAD 12
#define NT 261
#define NGL 197
#define CDIM 768
#define KT 14
#define PS_STRIDE 232
#define VT_STRIDE 232

__device__ __forceinline__ float bf2f(u16 u) {
    u32 x = ((u32)u) << 16;
    float f;
    __builtin_memcpy(&f, &x, 4);
    return f;
}
__device__ __forceinline__ u16 f2bf(float f) {
    u32 x;
    __builtin_memcpy(&x, &f, 4);
    x = (x + 0x7fffu + ((x >> 16) & 1u)) >> 16;
    return (u16)x;
}

#define GLD_LDS16(g, l) \
    __builtin_amdgcn_global_load_lds((const __attribute__((address_space(1))) void*)(g), \
                                     (__attribute__((address_space(3))) void*)(l), 16, 0, 0)
#define WAITV(n) asm volatile("s_waitcnt vmcnt(" #n ")" ::: "memory")
#define BARM() asm volatile("s_barrier" ::: "memory")

struct CvArgs {
    const float* in[4];
    u16* out[4];
    int n4[4];
};

// ---------------- wave-per-row LayerNorm, fp32 input ----------------
__device__ __forceinline__ void ln_row(const float* __restrict__ in, const float* __restrict__ w,
                                       const float* __restrict__ bia, u16* __restrict__ out,
                                       int row, int lane) {
    const float4* r = (const float4*)(in + (size_t)row * CDIM);
    float4 a = r[lane], b4 = r[lane + 64], c4 = r[lane + 128];
    float s  = a.x + a.y + a.z + a.w + b4.x + b4.y + b4.z + b4.w + c4.x + c4.y + c4.z + c4.w;
    float ss = a.x*a.x + a.y*a.y + a.z*a.z + a.w*a.w
             + b4.x*b4.x + b4.y*b4.y + b4.z*b4.z + b4.w*b4.w
             + c4.x*c4.x + c4.y*c4.y + c4.z*c4.z + c4.w*c4.w;
#pragma unroll
    for (int off = 32; off; off >>= 1) {
        s  += __shfl_xor(s, off);
        ss += __shfl_xor(ss, off);
    }
    float mu = s * (1.f / 768.f);
    float var = ss * (1.f / 768.f) - mu * mu;
    float inv = rsqrtf(var + 1e-5f);
    const float4* wp = (const float4*)w;
    const float4* bp = (const float4*)bia;
    u16* o = out + (size_t)row * CDIM;
#pragma unroll
    for (int t = 0; t < 3; ++t) {
        float4 v = (t == 0) ? a : (t == 1) ? b4 : c4;
        float4 ww = wp[lane + t * 64], bb = bp[lane + t * 64];
        u16x4 ov;
        ov[0] = f2bf((v.x - mu) * inv * ww.x + bb.x);
        ov[1] = f2bf((v.y - mu) * inv * ww.y + bb.y);
        ov[2] = f2bf((v.z - mu) * inv * ww.z + bb.z);
        ov[3] = f2bf((v.w - mu) * inv * ww.w + bb.w);
        *(u16x4*)(o + t * 256 + lane * 4) = ov;
    }
}

// ---------------- wave-per-row LayerNorm, bf16 input (x1) ----------------
__device__ __forceinline__ void ln_row_bf(const u16* __restrict__ in, const float* __restrict__ w,
                                          const float* __restrict__ bia, u16* __restrict__ out,
                                          int row, int lane) {
    const u16* r = in + (size_t)row * CDIM;
    float v[12];
#pragma unroll
    for (int t = 0; t < 3; ++t) {
        u16x4 u = *(const u16x4*)(r + t * 256 + lane * 4);
#pragma unroll
        for (int j = 0; j < 4; ++j) v[t * 4 + j] = bf2f(u[j]);
    }
    float s = 0.f, ss = 0.f;
#pragma unroll
    for (int j = 0; j < 12; ++j) { s += v[j]; ss += v[j] * v[j]; }
#pragma unroll
    for (int off = 32; off; off >>= 1) {
        s  += __shfl_xor(s, off);
        ss += __shfl_xor(ss, off);
    }
    float mu = s * (1.f / 768.f);
    float var = ss * (1.f / 768.f) - mu * mu;
    float inv = rsqrtf(var + 1e-5f);
    const float4* wp = (const float4*)w;
    const float4* bp = (const float4*)bia;
    u16* o = out + (size_t)row * CDIM;
#pragma unroll
    for (int t = 0; t < 3; ++t) {
        float4 ww = wp[lane + t * 64], bb = bp[lane + t * 64];
        u16x4 ov;
        ov[0] = f2bf((v[t * 4 + 0] - mu) * inv * ww.x + bb.x);
        ov[1] = f2bf((v[t * 4 + 1] - mu) * inv * ww.y + bb.y);
        ov[2] = f2bf((v[t * 4 + 2] - mu) * inv * ww.z + bb.z);
        ov[3] = f2bf((v[t * 4 + 3] - mu) * inv * ww.w + bb.w);
        *(u16x4*)(o + t * 256 + lane * 4) = ov;
    }
}

// y=0: weight fp32->bf16 conversion; y=1: LN1 (4 rows/block)
__global__ __launch_bounds__(256) void pre_k(const float* __restrict__ x, const float* __restrict__ w,
                                             const float* __restrict__ bia, u16* __restrict__ out,
                                             int nrows, CvArgs cv) {
    if (blockIdx.y == 0) {
        int i = blockIdx.x * 256 + threadIdx.x;
        int s0 = cv.n4[0], s1 = s0 + cv.n4[1], s2 = s1 + cv.n4[2], s3 = s2 + cv.n4[3];
        const float* in;
        u16* o;
        int base;
        if (i < s0)      { in = cv.in[0]; o = cv.out[0]; base = 0; }
        else if (i < s1) { in = cv.in[1]; o = cv.out[1]; base = s0; }
        else if (i < s2) { in = cv.in[2]; o = cv.out[2]; base = s1; }
        else if (i < s3) { in = cv.in[3]; o = cv.out[3]; base = s2; }
        else return;
        int j = i - base;
        float4 v = ((const float4*)in)[j];
        u16x4 ov;
        ov[0] = f2bf(v.x); ov[1] = f2bf(v.y); ov[2] = f2bf(v.z); ov[3] = f2bf(v.w);
        ((u16x4*)o)[j] = ov;
    } else {
        int lane = threadIdx.x & 63, wv = threadIdx.x >> 6;
        int row = blockIdx.x * 4 + wv;
        if (row < nrows) ln_row(x, w, bia, out, row, lane);
    }
}

__global__ __launch_bounds__(256) void ln_wbf(const u16* __restrict__ in, const float* __restrict__ w,
                                              const float* __restrict__ bia, u16* __restrict__ out, int nrows) {
    int lane = threadIdx.x & 63, wv = threadIdx.x >> 6;
    int row = blockIdx.x * 4 + wv;
    if (row < nrows) ln_row_bf(in, w, bia, out, row, lane);
}

// ---------------- high-occupancy GEMM (r14-proven): 128x128, BK=32, 32 KB LDS ----------------
// EPI: 1 = +bias +resid(fp32) -> bf16 (proj); 3 = +bias +resid(bf16) -> fp32 (fc2 -> d_out)
template <int EPI>
__global__ __launch_bounds__(256, 4) void gemm11(const u16* __restrict__ A, const u16* __restrict__ Bw,
                                                 int M, int N, int K, int nbn,
                                                 const float* __restrict__ bias,
                                                 const void* __restrict__ resid, void* __restrict__ outp) {
    __shared__ __align__(16) u16 sm[2][8192];
    const int tid = threadIdx.x;
    const int nwg = gridDim.x;
    const int q = nwg >> 3, r = nwg & 7;
    const int xcd = blockIdx.x & 7, within = blockIdx.x >> 3;
    const int id2 = (xcd < r ? xcd * (q + 1) : r * (q + 1) + (xcd - r) * q) + within;
    const int bm = id2 / nbn, bn = id2 % nbn;
    const int lane = tid & 63, wv = tid >> 6;
    const int wr = wv >> 1, wc = wv & 1;
    const int l15 = lane & 15, lg = lane >> 4;
    const int arow0 = bm * 128, brow0 = bn * 128;
    const int nt = K >> 5;

    const int srow = tid >> 2;
    const int sslot = tid & 3;
    const int sk = (sslot ^ ((srow >> 1) & 3)) * 8;
    const u16* gA[2];
    const u16* gB[2];
#pragma unroll
    for (int i = 0; i < 2; ++i) {
        int ar = arow0 + i * 64 + srow;
        if (ar >= M) ar = M - 1;
        gA[i] = A + (size_t)ar * K + sk;
        gB[i] = Bw + (size_t)(brow0 + i * 64 + srow) * K + sk;
    }

    auto STAGE = [&](int tt) {
        u16* sb = sm[tt & 1];
        const size_t ko = (size_t)tt * 32;
#pragma unroll
        for (int i = 0; i < 2; ++i) GLD_LDS16(gA[i] + ko, sb + i * 2048 + tid * 8);
#pragma unroll
        for (int i = 0; i < 2; ++i) GLD_LDS16(gB[i] + ko, sb + 4096 + i * 2048 + tid * 8);
    };

    f32x4 acc[4][4] = {};
    const int xb = (l15 >> 1) & 3;

    STAGE(0);
    for (int t = 0; t < nt; ++t) {
        if (t + 1 < nt) {
            STAGE(t + 1);
            WAITV(4);
        } else {
            WAITV(0);
        }
        BARM();
        const u16* sb = sm[t & 1];
        bf16x8 af[4], bq[4];
#pragma unroll
        for (int mi = 0; mi < 4; ++mi)
            af[mi] = *(const bf16x8*)(sb + (wr * 64 + mi * 16 + l15) * 32 + ((lg ^ xb) * 8));
#pragma unroll
        for (int ni = 0; ni < 4; ++ni)
            bq[ni] = *(const bf16x8*)(sb + 4096 + (wc * 64 + ni * 16 + l15) * 32 + ((lg ^ xb) * 8));
#pragma unroll
        for (int mi = 0; mi < 4; ++mi)
#pragma unroll
            for (int ni = 0; ni < 4; ++ni)
                acc[mi][ni] = __builtin_amdgcn_mfma_f32_16x16x32_bf16(af[mi], bq[ni], acc[mi][ni], 0, 0, 0);
        if (t + 2 < nt) BARM();
    }

#pragma unroll
    for (int mi = 0; mi < 4; ++mi) {
        int row0 = arow0 + wr * 64 + mi * 16 + lg * 4;
#pragma unroll
        for (int ni = 0; ni < 4; ++ni) {
            int col = brow0 + wc * 64 + ni * 16 + l15;
            float bb = bias[col];
#pragma unroll
            for (int rr = 0; rr < 4; ++rr) {
                int row = row0 + rr;
                if (row < M) {
                    float v = acc[mi][ni][rr] + bb;
                    if (EPI == 1) {
                        v += ((const float*)resid)[(size_t)row * N + col];
                        ((u16*)outp)[(size_t)row * N + col] = f2bf(v);
                    } else {
                        v += bf2f(((const u16*)resid)[(size_t)row * N + col]);
                        ((float*)outp)[(size_t)row * N + col] = v;
                    }
                }
            }
        }
    }
}

// ---------------- fc1 GEMM (r18-proven): 128x256 block, 8 waves, BK=32, 48 KB LDS ------------
__global__ __launch_bounds__(512, 3) void gemm14(const u16* __restrict__ A, const u16* __restrict__ Bw,
                                                 int M, int N, int K, int nbn,
                                                 const float* __restrict__ bias, void* __restrict__ outp) {
    __shared__ __align__(16) u16 sm[2][12288];
    const int tid = threadIdx.x;
    const int nwg = gridDim.x;
    const int q = nwg >> 3, r = nwg & 7;
    const int xcd = blockIdx.x & 7, within = blockIdx.x >> 3;
    const int id2 = (xcd < r ? xcd * (q + 1) : r * (q + 1) + (xcd - r) * q) + within;
    const int bm = id2 / nbn, bn = id2 % nbn;
    const int lane = tid & 63, wv = tid >> 6;
    const int wr = wv >> 2, wc = wv & 3;
    const int l15 = lane & 15, lg = lane >> 4;
    const int arow0 = bm * 128, brow0 = bn * 256;
    const int nt = K >> 5;

    const int srow = tid >> 2;
    const int sslot = tid & 3;
    const int sk = (sslot ^ ((srow >> 1) & 3)) * 8;
    int ar0 = arow0 + srow; if (ar0 >= M) ar0 = M - 1;
    const u16* gA0 = A + (size_t)ar0 * K + sk;
    const u16* gB[2];
#pragma unroll
    for (int i = 0; i < 2; ++i)
        gB[i] = Bw + (size_t)(brow0 + i * 128 + srow) * K + sk;

    auto STAGE = [&](int tt) {
        u16* sb = sm[tt & 1];
        const size_t ko = (size_t)tt * 32;
        GLD_LDS16(gA0 + ko, sb + tid * 8);
#pragma unroll
        for (int i = 0; i < 2; ++i)
            GLD_LDS16(gB[i] + ko, sb + 4096 + i * 4096 + tid * 8);
    };

    f32x4 acc[4][4] = {};
    const int xb = (l15 >> 1) & 3;

    STAGE(0);
    for (int t = 0; t < nt; ++t) {
        if (t + 1 < nt) {
            STAGE(t + 1);
            WAITV(3);
        } else {
            WAITV(0);
        }
        BARM();
        const u16* sb = sm[t & 1];
        bf16x8 af[4], bq[4];
#pragma unroll
        for (int mi = 0; mi < 4; ++mi)
            af[mi] = *(const bf16x8*)(sb + (wr * 64 + mi * 16 + l15) * 32 + ((lg ^ xb) * 8));
#pragma unroll
        for (int ni = 0; ni < 4; ++ni)
            bq[ni] = *(const bf16x8*)(sb + 4096 + (wc * 64 + ni * 16 + l15) * 32 + ((lg ^ xb) * 8));
#pragma unroll
        for (int mi = 0; mi < 4; ++mi)
#pragma unroll
            for (int ni = 0; ni < 4; ++ni)
                acc[mi][ni] = __builtin_amdgcn_mfma_f32_16x16x32_bf16(af[mi], bq[ni], acc[mi][ni], 0, 0, 0);
        if (t + 2 < nt) BARM();
    }

#pragma unroll
    for (int mi = 0; mi < 4; ++mi) {
        int row0 = arow0 + wr * 64 + mi * 16 + lg * 4;
#pragma unroll
        for (int ni = 0; ni < 4; ++ni) {
            int col = brow0 + wc * 64 + ni * 16 + l15;
            float bb = bias[col];
#pragma unroll
            for (int rr = 0; rr < 4; ++rr) {
                int row = row0 + rr;
                if (row < M) {
                    float v = acc[mi][ni][rr] + bb;
                    float z = v + 0.044715f * v * v * v;
                    v = v / (1.f + __expf(-1.5957691216f * z));
                    ((u16*)outp)[(size_t)row * N + col] = f2bf(v);
                }
            }
        }
    }
}

// ---------------- qkv GEMM, two zones (r17-proven) ----------------
__global__ __launch_bounds__(256, 4) void gemm_qkv(const u16* __restrict__ A, const u16* __restrict__ Bw,
                                                   u16* __restrict__ outp) {
    __shared__ __align__(16) u16 sm[2][8192];
    const int tid = threadIdx.x;
    const int nwg = gridDim.x;                  // 996
    const int q = nwg >> 3, r = nwg & 7;
    const int xcd = blockIdx.x & 7, within = blockIdx.x >> 3;
    const int id2 = (xcd < r ? xcd * (q + 1) : r * (q + 1) + (xcd - r) * q) + within;
    const bool kvz = (id2 >= 396);
    const int idz = kvz ? id2 - 396 : id2;
    const int bm = kvz ? idz / 12 : idz / 6;
    const int bn = kvz ? idz % 12 : idz % 6;
    const int Mz = kvz ? 6304 : 8352;
    const int colbase = kvz ? 768 + bn * 128 : bn * 128;
    const int lane = tid & 63, wv = tid >> 6;
    const int wr = wv >> 1, wc = wv & 1;
    const int l15 = lane & 15, lg = lane >> 4;
    const int arow0 = bm * 128;
    const int K = 768;
    const int nt = 24;

    const int srow = tid >> 2;
    const int sslot = tid & 3;
    const int sk = (sslot ^ ((srow >> 1) & 3)) * 8;
    const u16* gA[2];
    const u16* gB[2];
#pragma unroll
    for (int i = 0; i < 2; ++i) {
        int ar = arow0 + i * 64 + srow;
        if (ar >= Mz) ar = Mz - 1;
        int real = kvz ? (ar / 197) * 261 + (ar % 197) : ar;
        gA[i] = A + (size_t)real * K + sk;
        gB[i] = Bw + (size_t)(colbase + i * 64 + srow) * K + sk;
    }

    auto STAGE = [&](int tt) {
        u16* sb = sm[tt & 1];
        const size_t ko = (size_t)tt * 32;
#pragma unroll
        for (int i = 0; i < 2; ++i) GLD_LDS16(gA[i] + ko, sb + i * 2048 + tid * 8);
#pragma unroll
        for (int i = 0; i < 2; ++i) GLD_LDS16(gB[i] + ko, sb + 4096 + i * 2048 + tid * 8);
    };

    f32x4 acc[4][4] = {};
    const int xb = (l15 >> 1) & 3;

    STAGE(0);
    for (int t = 0; t < nt; ++t) {
        if (t + 1 < nt) {
            STAGE(t + 1);
            WAITV(4);
        } else {
            WAITV(0);
        }
        BARM();
        const u16* sb = sm[t & 1];
        bf16x8 af[4], bq[4];
#pragma unroll
        for (int mi = 0; mi < 4; ++mi)
            af[mi] = *(const bf16x8*)(sb + (wr * 64 + mi * 16 + l15) * 32 + ((lg ^ xb) * 8));
#pragma unroll
        for (int ni = 0; ni < 4; ++ni)
            bq[ni] = *(const bf16x8*)(sb + 4096 + (wc * 64 + ni * 16 + l15) * 32 + ((lg ^ xb) * 8));
#pragma unroll
        for (int mi = 0; mi < 4; ++mi)
#pragma unroll
            for (int ni = 0; ni < 4; ++ni)
                acc[mi][ni] = __builtin_amdgcn_mfma_f32_16x16x32_bf16(af[mi], bq[ni], acc[mi][ni], 0, 0, 0);
        if (t + 2 < nt) BARM();
    }

#pragma unroll
    for (int mi = 0; mi < 4; ++mi) {
        int row0 = arow0 + wr * 64 + mi * 16 + lg * 4;
#pragma unroll
        for (int ni = 0; ni < 4; ++ni) {
            int col = colbase + wc * 64 + ni * 16 + l15;
#pragma unroll
            for (int rr = 0; rr < 4; ++rr) {
                int row = row0 + rr;
                if (row < Mz) {
                    int real = kvz ? (row / 197) * 261 + (row % 197) : row;
                    outp[(size_t)real * 2304 + col] = f2bf(acc[mi][ni][rr]);
                }
            }
        }
    }
}

// ---------------- Fused attention (r8-proven): [0,1536) global MFMA, [1536,2048) neighborhood --
__global__ __launch_bounds__(256) void attn_fused(const u16* __restrict__ qkv, const float* __restrict__ ps,
                                                  u16* __restrict__ Z) {
    __shared__ __align__(16) u16 lds0[4 * 16 * PS_STRIDE];
    __shared__ __align__(16) u16 Vt[64 * VT_STRIDE];
    const int tid = threadIdx.x;
    const int lane = tid & 63, wv = tid >> 6;

    if (blockIdx.x >= 1536) {
        int idx = blockIdx.x - 1536;
        int b = idx >> 4;
        int m = (idx & 15) * 4 + wv;
        float px = ps[((size_t)b * 64 + m) * 2 + 0] * (1.f / 16.f);
        float py = ps[((size_t)b * 64 + m) * 2 + 1] * (1.f / 16.f);
        int c0 = min(max((int)floorf(px), 0), 13);
        int c1 = min(max((int)ceilf(px), 0), 13);
        int r0 = min(max((int)floorf(py), 0), 13);
        int r1 = min(max((int)ceilf(py), 0), 13);
        int tok[4];
        tok[0] = 1 + r0 * 14 + c0;
        tok[1] = 1 + r1 * 14 + c0;
        tok[2] = 1 + r0 * 14 + c1;
        tok[3] = 1 + r1 * 14 + c1;
        const size_t rowq = ((size_t)b * NT + NGL + m) * 2304;
#pragma unroll 1
        for (int h = 0; h < NHEAD; ++h) {
            float qv = bf2f(qkv[rowq + h * 64 + lane]);
            float a[4];
#pragma unroll
            for (int j = 0; j < 4; ++j) {
                float p = qv * bf2f(qkv[((size_t)b * NT + tok[j]) * 2304 + 768 + h * 64 + lane]);
#pragma unroll
                for (int off = 32; off; off >>= 1) p += __shfl_xor(p, off);
                a[j] = p;
            }
            float mx = fmaxf(fmaxf(a[0], a[1]), fmaxf(a[2], a[3]));
            float e0 = expf(a[0] - mx), e1 = expf(a[1] - mx), e2 = expf(a[2] - mx), e3 = expf(a[3] - mx);
            float inv = 1.f / (e0 + e1 + e2 + e3);
            float v0 = bf2f(qkv[((size_t)b * NT + tok[0]) * 2304 + 1536 + h * 64 + lane]);
            float v1 = bf2f(qkv[((size_t)b * NT + tok[1]) * 2304 + 1536 + h * 64 + lane]);
            float v2 = bf2f(qkv[((size_t)b * NT + tok[2]) * 2304 + 1536 + h * 64 + lane]);
            float v3 = bf2f(qkv[((size_t)b * NT + tok[3]) * 2304 + 1536 + h * 64 + lane]);
            float o = (e0 * v0 + e1 * v1 + e2 * v2 + e3 * v3) * inv;
            Z[((size_t)b * NT + NGL + m) * CDIM + h * 64 + lane] = f2bf(o);
        }
        return;
    }

    const int blk = blockIdx.x;
    const int qt = blk & 3;
    const int bh = blk >> 2;
    const int h = bh % NHEAD, b = bh / NHEAD;
    const int l15 = lane & 15, lg = lane >> 4;
    const u16* base = qkv + (size_t)b * NT * 2304;

    for (int c = tid; c < 224 * 8; c += 256) {
        int row = c >> 3, ch = c & 7;
        u16x8 v = {};
        if (row < NGL) v = *(const u16x8*)(base + (size_t)row * 2304 + 768 + h * 64 + ch * 8);
        int byte = row * 128 + ((ch * 16) ^ ((row & 7) << 4));
        *(u16x8*)((char*)lds0 + byte) = v;
    }
    for (int c = tid; c < 112 * 8; c += 256) {
        int mp = c >> 3, dch = c & 7;
        int m0 = mp * 2;
        u16x8 a0 = {}, a1 = {};
        if (m0 < NGL)     a0 = *(const u16x8*)(base + (size_t)m0 * 2304 + 1536 + h * 64 + dch * 8);
        if (m0 + 1 < NGL) a1 = *(const u16x8*)(base + (size_t)(m0 + 1) * 2304 + 1536 + h * 64 + dch * 8);
#pragma unroll
        for (int j = 0; j < 8; ++j) {
            u32 pk = (u32)a0[j] | ((u32)a1[j] << 16);
            *(u32*)((char*)Vt + (size_t)(dch * 8 + j) * (VT_STRIDE * 2) + m0 * 2) = pk;
        }
    }
    const int q0 = qt * 64 + wv * 16;
    int qrow = q0 + l15; if (qrow > NGL - 1) qrow = NGL - 1;
    bf16x8 aq0 = *(const bf16x8*)(base + (size_t)qrow * 2304 + h * 64 + lg * 8);
    bf16x8 aq1 = *(const bf16x8*)(base + (size_t)qrow * 2304 + h * 64 + 32 + lg * 8);
    __syncthreads();

    f32x4 s[KT];
    const int sw = (l15 & 7) << 4;
#pragma unroll
    for (int t = 0; t < KT; ++t) {
        const char* krow = (const char*)lds0 + (t * 16 + l15) * 128;
        bf16x8 bk0 = *(const bf16x8*)(krow + ((lg * 16) ^ sw));
        bf16x8 bk1 = *(const bf16x8*)(krow + ((64 + lg * 16) ^ sw));
        f32x4 acc = {};
        acc = __builtin_amdgcn_mfma_f32_16x16x32_bf16(aq0, bk0, acc, 0, 0, 0);
        acc = __builtin_amdgcn_mfma_f32_16x16x32_bf16(aq1, bk1, acc, 0, 0, 0);
        s[t] = acc * 0.125f;
    }
    float mx[4] = {-1e30f, -1e30f, -1e30f, -1e30f};
#pragma unroll
    for (int t = 0; t < KT; ++t)
#pragma unroll
        for (int r = 0; r < 4; ++r) mx[r] = fmaxf(mx[r], s[t][r]);
#pragma unroll
    for (int off = 1; off < 16; off <<= 1)
#pragma unroll
        for (int r = 0; r < 4; ++r) mx[r] = fmaxf(mx[r], __shfl_xor(mx[r], off));
    float sum[4] = {};
#pragma unroll
    for (int t = 0; t < KT; ++t) {
        bool valid = (t * 16 + l15) < NGL;
#pragma unroll
        for (int r = 0; r < 4; ++r) {
            float e = valid ? __expf(s[t][r] - mx[r]) : 0.f;
            s[t][r] = e;
            sum[r] += e;
        }
    }
#pragma unroll
    for (int off = 1; off < 16; off <<= 1)
#pragma unroll
        for (int r = 0; r < 4; ++r) sum[r] += __shfl_xor(sum[r], off);
    float inv[4];
#pragma unroll
    for (int r = 0; r < 4; ++r) inv[r] = 1.f / sum[r];

    __syncthreads();
    u16* Pw = lds0 + wv * 16 * PS_STRIDE;
#pragma unroll
    for (int t = 0; t < KT; ++t)
#pragma unroll
        for (int r = 0; r < 4; ++r)
            Pw[(4 * lg + r) * PS_STRIDE + t * 16 + l15] = f2bf(s[t][r] * inv[r]);

    f32x4 o[4] = {};
#pragma unroll
    for (int ks = 0; ks < 7; ++ks) {
        bf16x8 pa = *(const bf16x8*)(Pw + l15 * PS_STRIDE + ks * 32 + lg * 8);
#pragma unroll
        for (int dt = 0; dt < 4; ++dt) {
            bf16x8 bv = *(const bf16x8*)((const char*)Vt + (size_t)(dt * 16 + l15) * (VT_STRIDE * 2) + ks * 64 + lg * 16);
            o[dt] = __builtin_amdgcn_mfma_f32_16x16x32_bf16(pa, bv, o[dt], 0, 0, 0);
        }
    }
#pragma unroll
    for (int dt = 0; dt < 4; ++dt)
#pragma unroll
        for (int r = 0; r < 4; ++r) {
            int q = q0 + 4 * lg + r;
            if (q < NGL) Z[((size_t)b * NT + q) * CDIM + h * 64 + dt * 16 + l15] = f2bf(o[dt][r]);
        }
}

extern "C" void kernel_launch(void* const* d_in, const int* in_sizes, int n_in,
                              void* d_out, int out_size, void* d_ws, size_t ws_size,
                              hipStream_t stream) {
    const float* x      = (const float*)d_in[0];
    const float* ps     = (const float*)d_in[1];
    const float* n1w    = (const float*)d_in[3];
    const float* n1b    = (const float*)d_in[4];
    const float* qkv_w  = (const float*)d_in[5];
    const float* proj_w = (const float*)d_in[6];
    const float* proj_b = (const float*)d_in[7];
    const float* n2w    = (const float*)d_in[8];
    const float* n2b    = (const float*)d_in[9];
    const float* fc1_w  = (const float*)d_in[10];
    const float* fc1_b  = (const float*)d_in[11];
    const float* fc2_w  = (const float*)d_in[12];
    const float* fc2_b  = (const float*)d_in[13];

    char* ws = (char*)d_ws;
    const int M = 32 * NT;  // 8352
    u16* hbuf  = (u16*)ws;                               // 12,828,672 B
    u16* qkvb  = (u16*)(ws + 12828672);                  // 38,486,016 B
    u16* Zb    = (u16*)(ws + 12828672 + 38486016);       // 12,828,672 B
    u16* Gb    = (u16*)(ws + 12828672);                  // 51,314,688 B (aliases qkv+Z, both dead)
    u16* x1    = (u16*)(ws + 64143360);                  // bf16, 12,828,672 B
    u16* wq    = (u16*)(ws + 89800704);
    u16* wp    = wq + 2304 * 768;
    u16* w1    = wp + 768 * 768;
    u16* w2    = w1 + 3072 * 768;

    CvArgs cv;
    cv.in[0] = qkv_w;  cv.out[0] = wq; cv.n4[0] = 2304 * 768 / 4;
    cv.in[1] = proj_w; cv.out[1] = wp; cv.n4[1] = 768 * 768 / 4;
    cv.in[2] = fc1_w;  cv.out[2] = w1; cv.n4[2] = 3072 * 768 / 4;
    cv.in[3] = fc2_w;  cv.out[3] = w2; cv.n4[3] = 768 * 3072 / 4;

    pre_k<<<dim3(6912, 2), 256, 0, stream>>>(x, n1w, n1b, hbuf, M, cv);
    gemm_qkv<<<996, 256, 0, stream>>>(hbuf, wq, qkvb);
    attn_fused<<<2048, 256, 0, stream>>>(qkvb, ps, Zb);
    gemm11<1><<<66 * 6, 256, 0, stream>>>(Zb, wp, M, 768, 768, 6, proj_b, x, x1);
    ln_wbf<<<2088, 256, 0, stream>>>(x1, n2w, n2b, hbuf, M);
    gemm14<<<66 * 12, 512, 0, stream>>>(hbuf, w1, M, 3072, 768, 12, fc1_b, Gb);
    gemm11<3><<<66 * 6, 256, 0, stream>>>(Gb, w2, M, 768, 3072, 6, fc2_b, x1, (float*)d_out);
}